// Round 4
// baseline (979.215 us; speedup 1.0000x reference)
//
#include <hip/hip_runtime.h>
#include <hip/hip_bf16.h>
#include <math.h>

// ---------- problem constants ----------
#define BB 4
#define LL 1024
#define DD 512
#define DI 1024
#define NST 16
#define NC 64   // scan chunks
#define CL 16   // chunk length

typedef unsigned short ushort_t;
typedef __attribute__((ext_vector_type(8))) short short8;
typedef __attribute__((ext_vector_type(4))) float f32x4;
typedef __attribute__((ext_vector_type(4))) unsigned short ushort4_t;

__device__ __forceinline__ float silu_f(float x) { return x / (1.f + __expf(-x)); }

__device__ __forceinline__ ushort_t f2bf(float f) {
  union { float f; unsigned u; } v; v.f = f;
  unsigned r = v.u + 0x7fffu + ((v.u >> 16) & 1u);
  return (ushort_t)(r >> 16);
}
__device__ __forceinline__ float bf2f(ushort_t h) {
  union { unsigned u; float f; } v; v.u = ((unsigned)h) << 16;
  return v.f;
}

__device__ __forceinline__ void gl_lds16(const ushort_t* src, ushort_t* dst) {
  __builtin_amdgcn_global_load_lds(
      (const __attribute__((address_space(1))) void*)src,
      (__attribute__((address_space(3))) void*)dst, 16, 0, 0);
}

// ======================= bf16 MFMA GEMM =======================
// C[m,n] = op( sum_k A[m,k]*Bt[n,k] + bias );  A: M x K bf16, Bt: N x K bf16
// BM=128, BK=64, 4 waves. BN=128: wave grid 2x2 (64x64/wave). BN=64: 4x1 (32x64).
// ACT: 0 none 1 silu 2 gelu 3 softplus ; BIASM: 0 none 1 col 2 row
// CMODE: 0 store, 1 += , 2 atomicAdd (f32 only)
// FLIPA/FLIPC: row ^ 1023 ; OUTBF: C bf16
// SPLITK: blockIdx.z = k-split index, K = per-split k count (bias applied by z==0 only)
template <int BN, int ACT, int BIASM, int CMODE, int FLIPA, int FLIPC, int OUTBF, int SPLITK>
__global__ __launch_bounds__(256) void mgemm(
    const ushort_t* __restrict__ A, const ushort_t* __restrict__ Bt,
    const float* __restrict__ bias, void* __restrict__ Cv,
    int K, int lda, int ldb, int ldc, int nreal,
    long sA, long sB, long sC, float scale) {
  constexpr int MREP = (BN == 128) ? 4 : 2;
  constexpr int WM = MREP * 16;          // per-wave M span
  constexpr int NB = BN / 32;            // B staging chunks per wave
  __shared__ ushort_t As[128 * 64];
  __shared__ ushort_t Bs[BN * 64];
  const int zz = blockIdx.z;
  const ushort_t* Ab = A + (SPLITK ? (long)zz * K : zz * sA);
  const ushort_t* Bb = Bt + (SPLITK ? (long)zz * K : zz * sB);
  // XCD-aware bijective swizzle (nwg divisible by 8 for all call sites)
  const int flat = blockIdx.y * gridDim.x + blockIdx.x;
  const int nwg = gridDim.x * gridDim.y;
  const int id2 = (flat & 7) * (nwg >> 3) + (flat >> 3);
  const int bm = (id2 / gridDim.x) * 128;
  const int bn = (id2 % gridDim.x) * BN;
  const int tid = threadIdx.x;
  const int wave = tid >> 6, lane = tid & 63;
  const int rlo = lane & 15, q = lane >> 4;
  const int wr = (BN == 128) ? (wave >> 1) : wave;
  const int wc = (BN == 128) ? (wave & 1) : 0;

  f32x4 zero4 = {0.f, 0.f, 0.f, 0.f};
  f32x4 acc[MREP][4];
#pragma unroll
  for (int m = 0; m < MREP; ++m)
#pragma unroll
    for (int n = 0; n < 4; ++n) acc[m][n] = zero4;

  // staging: chunk c covers LDS bytes [c*1024, c*1024+1024)
  // lane writes 16B at c*1024+lane*16 -> row=c*8+lane/8, slot=lane&7
  // LDS[row][slot] holds global col-chunk (slot ^ (row&7))  (XOR involution)
  const int srow_off = lane >> 3;
  const int sslot = lane & 7;

  for (int k0 = 0; k0 < K; k0 += 64) {
    __syncthreads();
#pragma unroll
    for (int it = 0; it < 4; ++it) {
      int c = wave * 4 + it;
      int row = c * 8 + srow_off;
      int gcol = ((sslot ^ (row & 7)) << 3);
      int gra = bm + row;
      if (FLIPA) gra ^= 1023;
      gl_lds16(Ab + (long)gra * lda + k0 + gcol, &As[c * 512]);
    }
#pragma unroll
    for (int it = 0; it < NB; ++it) {
      int c = wave * NB + it;
      int row = c * 8 + srow_off;
      int gcol = ((sslot ^ (row & 7)) << 3);
      gl_lds16(Bb + (long)(bn + row) * ldb + k0 + gcol, &Bs[c * 512]);
    }
    __syncthreads();
#pragma unroll
    for (int ks = 0; ks < 2; ++ks) {
      short8 af[MREP], bf[4];
#pragma unroll
      for (int m = 0; m < MREP; ++m) {
        int row = wr * WM + m * 16 + rlo;
        int ch = (ks * 4 + q) ^ (row & 7);
        af[m] = *(const short8*)&As[row * 64 + ch * 8];
      }
#pragma unroll
      for (int n = 0; n < 4; ++n) {
        int row = wc * 64 + n * 16 + rlo;
        int ch = (ks * 4 + q) ^ (row & 7);
        bf[n] = *(const short8*)&Bs[row * 64 + ch * 8];
      }
#pragma unroll
      for (int m = 0; m < MREP; ++m)
#pragma unroll
        for (int n = 0; n < 4; ++n)
          acc[m][n] = __builtin_amdgcn_mfma_f32_16x16x32_bf16(af[m], bf[n], acc[m][n], 0, 0, 0);
    }
  }

  // epilogue: C/D layout col=lane&15, row=q*4+j  [m89]
#pragma unroll
  for (int m = 0; m < MREP; ++m) {
#pragma unroll
    for (int n = 0; n < 4; ++n) {
      int col = bn + wc * 64 + n * 16 + rlo;
      bool cok = (col < nreal);
#pragma unroll
      for (int j = 0; j < 4; ++j) {
        int row = bm + wr * WM + m * 16 + q * 4 + j;
        int orow = FLIPC ? (row ^ 1023) : row;
        float v = acc[m][n][j];
        if (!SPLITK || zz == 0) {
          if (BIASM == 1) v += bias[col];
          else if (BIASM == 2) v += bias[row];
        }
        if (ACT == 1) v = silu_f(v);
        else if (ACT == 2) v = 0.5f * v * (1.f + erff(v * 0.70710678118654752f));
        else if (ACT == 3) v = (v > 20.f) ? v : log1pf(__expf(v));
        if (cok) {
          if (OUTBF) {
            ushort_t* C = (ushort_t*)Cv + (SPLITK ? 0 : zz * sC);
            C[(long)orow * ldc + col] = f2bf(scale * v);
          } else {
            float* C = (float*)Cv + (SPLITK ? 0 : zz * sC);
            if (CMODE == 2) atomicAdd(&C[(long)orow * ldc + col], scale * v);
            else if (CMODE == 1) C[(long)orow * ldc + col] += scale * v;
            else C[(long)orow * ldc + col] = scale * v;
          }
        }
      }
    }
  }
}

// ======================= fused f32 -> bf16 weight conversion =======================
#define NSEG 10
struct CvtArgs {
  const float* src[NSEG];
  ushort_t* dst[NSEG];
  int start4[NSEG];  // prefix offsets in float4 units
};
__global__ __launch_bounds__(256) void cvt_all_kernel(CvtArgs a, int total4) {
  int i = blockIdx.x * 256 + threadIdx.x;
  int stride = gridDim.x * 256;
  for (; i < total4; i += stride) {
    int seg = 0;
#pragma unroll
    for (int s = 1; s < NSEG; ++s)
      if (i >= a.start4[s]) seg = s;
    int off = i - a.start4[seg];
    float4 v = ((const float4*)a.src[seg])[off];
    ushort4_t o;
    o.x = f2bf(v.x); o.y = f2bf(v.y); o.z = f2bf(v.z); o.w = f2bf(v.w);
    *(ushort4_t*)(a.dst[seg] + (long)off * 4) = o;
  }
}

// plain cvt (x -> bf16, locals phase)
__global__ __launch_bounds__(256) void cvt_kernel(const float* __restrict__ in,
                                                  ushort_t* __restrict__ out, long n) {
  long i = (long)blockIdx.x * 256 + threadIdx.x;
  long stride = (long)gridDim.x * 256;
  for (; i < n; i += stride) out[i] = f2bf(in[i]);
}

// zero-fill f32 (float4 granularity)
__global__ __launch_bounds__(256) void zf_kernel(float* __restrict__ p) {
  int i = blockIdx.x * 256 + threadIdx.x;
  float4 z = {0.f, 0.f, 0.f, 0.f};
  ((float4*)p)[i] = z;
}

// ======================= LayerNorm (wave per row, D=512) -> bf16 =======================
__global__ __launch_bounds__(256) void ln_kernel(
    const float* __restrict__ x, const float* __restrict__ w,
    const float* __restrict__ b, ushort_t* __restrict__ o) {
  int row = blockIdx.x * 4 + (threadIdx.x >> 6);
  int lane = threadIdx.x & 63;
  const float* xr = x + (long)row * DD + lane * 8;
  float v[8];
  *(float4*)&v[0] = *(const float4*)&xr[0];
  *(float4*)&v[4] = *(const float4*)&xr[4];
  float s = 0.f, qq = 0.f;
#pragma unroll
  for (int k = 0; k < 8; ++k) { s += v[k]; qq += v[k] * v[k]; }
#pragma unroll
  for (int off = 1; off < 64; off <<= 1) {
    s += __shfl_xor(s, off);
    qq += __shfl_xor(qq, off);
  }
  float mean = s * (1.f / DD);
  float rs = rsqrtf(qq * (1.f / DD) - mean * mean + 1e-5f);
  int c = lane * 8;
  short8 ov;
#pragma unroll
  for (int k = 0; k < 8; ++k)
    ov[k] = (short)f2bf((v[k] - mean) * rs * w[c + k] + b[c + k]);
  *(short8*)&o[(long)row * DD + c] = ov;
}

// ============== InstanceNorm over L + SiLU, in place (f32) ==============
__global__ __launch_bounds__(256) void inorm_silu_kernel(float* __restrict__ h) {
  long row = blockIdx.x;
  float* p = h + row * (long)LL;
  int t = threadIdx.x;
  float4 v = *(const float4*)&p[t * 4];
  float s = v.x + v.y + v.z + v.w;
  float q = v.x * v.x + v.y * v.y + v.z * v.z + v.w * v.w;
#pragma unroll
  for (int off = 1; off < 64; off <<= 1) {
    s += __shfl_xor(s, off);
    q += __shfl_xor(q, off);
  }
  __shared__ float ss[4], sq[4];
  int wv = t >> 6;
  if ((t & 63) == 0) { ss[wv] = s; sq[wv] = q; }
  __syncthreads();
  s = ss[0] + ss[1] + ss[2] + ss[3];
  q = sq[0] + sq[1] + sq[2] + sq[3];
  float mean = s * (1.f / LL);
  float rs = rsqrtf(q * (1.f / LL) - mean * mean + 1e-5f);
  v.x = silu_f((v.x - mean) * rs);
  v.y = silu_f((v.y - mean) * rs);
  v.z = silu_f((v.z - mean) * rs);
  v.w = silu_f((v.w - mean) * rs);
  *(float4*)&p[t * 4] = v;
}

// ============== Mamba causal depthwise conv (KC=4) + bias + SiLU (bf16 in/out) ==============
__global__ __launch_bounds__(256) void mconv_kernel(
    const ushort_t* __restrict__ xz, const float* __restrict__ cw,
    const float* __restrict__ cb, ushort_t* __restrict__ xc) {
  long i = (long)blockIdx.x * 256 + threadIdx.x;  // over B*L*DI
  int d = (int)(i & (DI - 1));
  long bt = i >> 10;
  int t = (int)(bt & (LL - 1));
  const ushort_t* col = xz + d;
  long r = bt * (2 * DI);
  float w0 = cw[d * 4 + 0], w1 = cw[d * 4 + 1], w2 = cw[d * 4 + 2], w3 = cw[d * 4 + 3];
  float acc = cb[d];
  if (t >= 3) acc += bf2f(col[r - 3 * 2 * DI]) * w0;
  if (t >= 2) acc += bf2f(col[r - 2 * 2 * DI]) * w1;
  if (t >= 1) acc += bf2f(col[r - 1 * 2 * DI]) * w2;
  acc += bf2f(col[r]) * w3;
  xc[i] = f2bf(silu_f(acc));
}

// ============== local depthwise conv over L, 'same' padding (f32) ==============
template <int KW>
__global__ __launch_bounds__(256) void dwconv_kernel(
    const float* __restrict__ in, const float* __restrict__ w, float* __restrict__ out) {
  long i = (long)blockIdx.x * 256 + threadIdx.x;  // over B*D*L
  int l = (int)(i & (LL - 1));
  long bd = i >> 10;
  int d = (int)(bd & (DD - 1));
  const float* row = in + bd * (long)LL;
  float acc = 0.f;
#pragma unroll
  for (int j = 0; j < KW; ++j) {
    int ll = l + j - KW / 2;
    if (ll >= 0 && ll < LL) acc += row[ll] * w[d * KW + j];
  }
  out[i] = acc;
}

// ============== transpose (B, D, L) f32 -> (B, L, D) bf16 ==============
__global__ void transpose_dl_kernel(const float* __restrict__ in, ushort_t* __restrict__ out) {
  __shared__ float tile[32][33];
  int b = blockIdx.z;
  int l0 = blockIdx.x * 32, d0 = blockIdx.y * 32;
  int tx = threadIdx.x, ty = threadIdx.y;  // (32, 8)
  const float* ib = in + (long)b * DD * LL;
  ushort_t* ob = out + (long)b * LL * DD;
#pragma unroll
  for (int r = 0; r < 4; ++r)
    tile[ty + 8 * r][tx] = ib[(long)(d0 + ty + 8 * r) * LL + l0 + tx];
  __syncthreads();
#pragma unroll
  for (int r = 0; r < 4; ++r)
    ob[(long)(l0 + ty + 8 * r) * DD + d0 + tx] = f2bf(tile[tx][ty + 8 * r]);
}

// ============== g (f32) -> cat bf16 columns [0,512) ==============
__global__ __launch_bounds__(256) void copyg_kernel(const float* __restrict__ g,
                                                    ushort_t* __restrict__ cat) {
  long i = (long)blockIdx.x * 256 + threadIdx.x;  // 4096*512
  long r = i >> 9;
  int c = (int)(i & 511);
  cat[r * 1536 + c] = f2bf(g[i]);
}

// ======================= selective scan, 3-pass chunked (NC=64, CL=16) =======================
__global__ __launch_bounds__(256) void scan1_kernel(
    const ushort_t* __restrict__ dt, const ushort_t* __restrict__ xc,
    const float* __restrict__ xdb, const float* __restrict__ A_log,
    float* __restrict__ hend, float* __restrict__ dts) {
  int idx = blockIdx.x * 256 + threadIdx.x;  // B*NC*DI = 262144
  int d = idx & (DI - 1);
  int c = (idx >> 10) & (NC - 1);
  int b = idx >> 16;
  float Ac[NST];
  {
    const float4* ap = (const float4*)(A_log + d * NST);
#pragma unroll
    for (int k = 0; k < 4; ++k) {
      float4 a = ap[k];
      Ac[4 * k + 0] = -__expf(a.x);
      Ac[4 * k + 1] = -__expf(a.y);
      Ac[4 * k + 2] = -__expf(a.z);
      Ac[4 * k + 3] = -__expf(a.w);
    }
  }
  long rowbase = (long)b * LL + c * CL;
  float ldts[CL], lxs[CL];
#pragma unroll
  for (int tt = 0; tt < CL; ++tt) {
    long r = rowbase + tt;
    ldts[tt] = bf2f(dt[r * DI + d]);
    lxs[tt] = bf2f(xc[r * DI + d]);
  }
  float h[NST] = {};
  float ds = 0.f;
#pragma unroll
  for (int tt = 0; tt < CL; ++tt) {
    ds += ldts[tt];
    float coef = ldts[tt] * lxs[tt];
    const float4* brow = (const float4*)&xdb[(rowbase + tt) * 64 + 32];
    float bv[NST];
#pragma unroll
    for (int k = 0; k < 4; ++k) {
      float4 bb = brow[k];
      bv[4 * k + 0] = bb.x; bv[4 * k + 1] = bb.y; bv[4 * k + 2] = bb.z; bv[4 * k + 3] = bb.w;
    }
#pragma unroll
    for (int n = 0; n < NST; ++n) h[n] = h[n] * __expf(Ac[n] * ldts[tt]) + coef * bv[n];
  }
  long o = ((long)(b * DI + d) * NC + c) * NST;
  float4* ho = (float4*)(hend + o);
#pragma unroll
  for (int k = 0; k < 4; ++k) {
    float4 hv = {h[4 * k], h[4 * k + 1], h[4 * k + 2], h[4 * k + 3]};
    ho[k] = hv;
  }
  dts[((long)b * NC + c) * DI + d] = ds;
}

__global__ __launch_bounds__(256) void scan2_kernel(
    const float* __restrict__ hend, const float* __restrict__ dts,
    const float* __restrict__ A_log, float* __restrict__ carries) {
  int idx = blockIdx.x * 256 + threadIdx.x;  // B*DI*NST = 65536
  int n = idx & (NST - 1);
  int d = (idx >> 4) & (DI - 1);
  int b = idx >> 14;
  float Ac = -__expf(A_log[d * NST + n]);
  float e[NC];
#pragma unroll
  for (int c = 0; c < NC; ++c)
    e[c] = __expf(Ac * dts[((long)b * NC + c) * DI + d]);
  float carry = 0.f;
  long base = (long)(b * DI + d) * NC * NST + n;
#pragma unroll
  for (int c = 0; c < NC; ++c) {
    carries[base + c * NST] = carry;
    carry = carry * e[c] + hend[base + c * NST];
  }
}

__global__ __launch_bounds__(256) void scan3_kernel(
    const ushort_t* __restrict__ dt, const ushort_t* __restrict__ xc,
    const float* __restrict__ xdb, const float* __restrict__ A_log,
    const float* __restrict__ carries, const float* __restrict__ Dp,
    const ushort_t* __restrict__ xz, ushort_t* __restrict__ y) {
  int idx = blockIdx.x * 256 + threadIdx.x;
  int d = idx & (DI - 1);
  int c = (idx >> 10) & (NC - 1);
  int b = idx >> 16;
  float Ac[NST];
  {
    const float4* ap = (const float4*)(A_log + d * NST);
#pragma unroll
    for (int k = 0; k < 4; ++k) {
      float4 a = ap[k];
      Ac[4 * k + 0] = -__expf(a.x);
      Ac[4 * k + 1] = -__expf(a.y);
      Ac[4 * k + 2] = -__expf(a.z);
      Ac[4 * k + 3] = -__expf(a.w);
    }
  }
  float h[NST];
  long o = ((long)(b * DI + d) * NC + c) * NST;
  {
    const float4* co = (const float4*)(carries + o);
#pragma unroll
    for (int k = 0; k < 4; ++k) {
      float4 cv = co[k];
      h[4 * k + 0] = cv.x; h[4 * k + 1] = cv.y; h[4 * k + 2] = cv.z; h[4 * k + 3] = cv.w;
    }
  }
  float Dv = Dp[d];
  long rowbase = (long)b * LL + c * CL;
  float ldts[CL], lxs[CL];
#pragma unroll
  for (int tt = 0; tt < CL; ++tt) {
    long r = rowbase + tt;
    ldts[tt] = bf2f(dt[r * DI + d]);
    lxs[tt] = bf2f(xc[r * DI + d]);
  }
#pragma unroll
  for (int tt = 0; tt < CL; ++tt) {
    long r = rowbase + tt;
    float coef = ldts[tt] * lxs[tt];
    const float4* brow = (const float4*)&xdb[r * 64 + 32];
    float bv[NST], cv[NST];
#pragma unroll
    for (int k = 0; k < 4; ++k) {
      float4 bb = brow[k];
      bv[4 * k + 0] = bb.x; bv[4 * k + 1] = bb.y; bv[4 * k + 2] = bb.z; bv[4 * k + 3] = bb.w;
      float4 cc = brow[k + 4];
      cv[4 * k + 0] = cc.x; cv[4 * k + 1] = cc.y; cv[4 * k + 2] = cc.z; cv[4 * k + 3] = cc.w;
    }
    float acc = 0.f;
#pragma unroll
    for (int n = 0; n < NST; ++n) {
      h[n] = h[n] * __expf(Ac[n] * ldts[tt]) + coef * bv[n];
      acc += h[n] * cv[n];
    }
    float yv = acc + lxs[tt] * Dv;
    float zv = bf2f(xz[r * (2 * DI) + DI + d]);
    y[r * DI + d] = f2bf(yv * silu_f(zv));
  }
}

// ======================= f32 tiled GEMM (dt-proj only, K=32) =======================
template <int ACT, int BIASM, int OUTBF>
__global__ __launch_bounds__(256) void gemm_kernel(
    const float* __restrict__ A, const float* __restrict__ Bt,
    const float* __restrict__ bias, void* __restrict__ Cv,
    int K, int lda, int ldb, int ldc, float scale) {
  const int bm = blockIdx.y * 64, bn = blockIdx.x * 64;
  __shared__ float As[64][32];
  __shared__ float Bs[32][64];
  const int tid = threadIdx.x;
  const int tx = tid & 15, ty = tid >> 4;
  float acc[4][4] = {};
  for (int k0 = 0; k0 < K; k0 += 32) {
#pragma unroll
    for (int it = 0; it < 2; ++it) {
      int e = tid + it * 256;
      int r = e >> 3;
      int kq = (e & 7) << 2;
      float4 va = *(const float4*)(A + (long)(bm + r) * lda + k0 + kq);
      *(float4*)&As[r][kq] = va;
      float4 vb = *(const float4*)(Bt + (long)(bn + r) * ldb + k0 + kq);
      Bs[kq + 0][r] = vb.x;
      Bs[kq + 1][r] = vb.y;
      Bs[kq + 2][r] = vb.z;
      Bs[kq + 3][r] = vb.w;
    }
    __syncthreads();
#pragma unroll
    for (int kk = 0; kk < 32; kk += 4) {
      float4 a4[4], b4[4];
#pragma unroll
      for (int i = 0; i < 4; ++i) a4[i] = *(const float4*)&As[ty * 4 + i][kk];
#pragma unroll
      for (int c = 0; c < 4; ++c) b4[c] = *(const float4*)&Bs[kk + c][tx * 4];
#pragma unroll
      for (int c = 0; c < 4; ++c) {
        float4 bb = b4[c];
#pragma unroll
        for (int i = 0; i < 4; ++i) {
          float av = (c == 0) ? a4[i].x : (c == 1) ? a4[i].y : (c == 2) ? a4[i].z : a4[i].w;
          acc[i][0] += av * bb.x;
          acc[i][1] += av * bb.y;
          acc[i][2] += av * bb.z;
          acc[i][3] += av * bb.w;
        }
      }
    }
    __syncthreads();
  }
#pragma unroll
  for (int i = 0; i < 4; ++i) {
    int row = bm + ty * 4 + i;
#pragma unroll
    for (int j = 0; j < 4; ++j) {
      int col = bn + tx * 4 + j;
      float v = acc[i][j];
      if (BIASM == 1) v += bias[col];
      else if (BIASM == 2) v += bias[row];
      if (ACT == 1) v = silu_f(v);
      else if (ACT == 2) v = 0.5f * v * (1.f + erff(v * 0.70710678118654752f));
      else if (ACT == 3) v = (v > 20.f) ? v : log1pf(__expf(v));
      if (OUTBF) ((ushort_t*)Cv)[(long)row * ldc + col] = f2bf(scale * v);
      else ((float*)Cv)[(long)row * ldc + col] = scale * v;
    }
  }
}

// ======================= host launch =======================
extern "C" void kernel_launch(void* const* d_in, const int* in_sizes, int n_in,
                              void* d_out, int out_size, void* d_ws, size_t ws_size,
                              hipStream_t stream) {
  const float* x        = (const float*)d_in[0];
  const float* in_w     = (const float*)d_in[1];
  const float* in_b     = (const float*)d_in[2];
  const float* conv_w   = (const float*)d_in[3];
  const float* conv_b   = (const float*)d_in[4];
  const float* xp_w     = (const float*)d_in[5];
  const float* dt_w     = (const float*)d_in[6];
  const float* dt_b     = (const float*)d_in[7];
  const float* A_log    = (const float*)d_in[8];
  const float* Dp       = (const float*)d_in[9];
  const float* out_w    = (const float*)d_in[10];
  const float* out_b    = (const float*)d_in[11];
  const float* ln_w     = (const float*)d_in[12];
  const float* ln_b     = (const float*)d_in[13];
  const float* ffn_ln_w = (const float*)d_in[14];
  const float* ffn_ln_b = (const float*)d_in[15];
  const float* ffn_w1   = (const float*)d_in[16];
  const float* ffn_b1   = (const float*)d_in[17];
  const float* ffn_w2   = (const float*)d_in[18];
  const float* ffn_b2   = (const float*)d_in[19];
  const float* l5_pw1w  = (const float*)d_in[20];
  const float* l5_pw1b  = (const float*)d_in[21];
  const float* l5_dww   = (const float*)d_in[22];
  const float* l5_pw2w  = (const float*)d_in[23];
  const float* l5_pw2b  = (const float*)d_in[24];
  const float* l7_pw1w  = (const float*)d_in[25];
  const float* l7_pw1b  = (const float*)d_in[26];
  const float* l7_dww   = (const float*)d_in[27];
  const float* l7_pw2w  = (const float*)d_in[28];
  const float* l7_pw2b  = (const float*)d_in[29];
  const float* proj_w   = (const float*)d_in[30];
  const float* proj_b   = (const float*)d_in[31];
  float* outp = (float*)d_out;

  // ---------- workspace layout ----------
  const long N_BLD = (long)BB * LL * DD;  // 2,097,152
  ushort_t* wb_in  = (ushort_t*)d_ws;          // 4,194,304
  ushort_t* wb_out = wb_in + 4194304;          // 2,097,152
  ushort_t* wb_xp  = wb_out + 2097152;         // 262,144 (4 x 64 x 1024)
  ushort_t* wb_f1  = wb_xp + 262144;           // 2,097,152
  ushort_t* wb_f2  = wb_f1 + 2097152;          // 2,097,152
  ushort_t* wb_pw1 = wb_f2 + 2097152;          // 524,288 (k5 @0, k7 @262144)
  ushort_t* wb_pw2 = wb_pw1 + 524288;          // 524,288
  ushort_t* wb_proj= wb_pw2 + 524288;          // 786,432
  ushort_t* xnb    = wb_proj + 786432;         // 2,097,152 bf16
  float* g = (float*)(xnb + 2097152);          // 2,097,152 f32
  char* arena = (char*)(g + 2097152);
  // mamba/ffn phase
  ushort_t* xzb = (ushort_t*)arena;            // 8,388,608 ushort (4096 x 2048)
  ushort_t* xcb = xzb + 8388608;               // 4,194,304 ushort
  float* xdb  = (float*)(xcb + 4194304);       // 262,144 f32
  ushort_t* dtb = (ushort_t*)(xdb + 262144);   // 4,194,304 ushort
  ushort_t* yb = dtb + 4194304;                // 4,194,304 ushort
  float* hend = (float*)(yb + 4194304);        // 4,194,304 f32
  float* dts  = hend + 4194304;                // 262,144 f32
  float* car  = dts + 262144;                  // 4,194,304 f32
  ushort_t* h1b = (ushort_t*)hend;             // 8,388,608 ushort (FFN h1; hend dead by FFN)
  // locals overlay (mamba scratch dead)
  ushort_t* xbf = (ushort_t*)arena;            // 2,097,152 ushort
  float* lh  = (float*)(xbf + 2097152);        // 2,097,152 f32
  float* lhc = lh + 2097152;                   // 2,097,152 f32
  ushort_t* lhT = (ushort_t*)(lhc + 2097152);  // 2,097,152 ushort
  ushort_t* cat = lhT + 2097152;               // 6,291,456 ushort
  size_t need = (size_t)((char*)(car + 4194304) - (char*)d_ws);
  if (ws_size < need) return;

  // ---------- fused weight conversions (bf16) ----------
  {
    CvtArgs ca;
    const float* srcs[NSEG] = {in_w, out_w, xp_w, ffn_w1, ffn_w2,
                               l5_pw1w, l7_pw1w, l5_pw2w, l7_pw2w, proj_w};
    ushort_t* dsts[NSEG] = {wb_in, wb_out, wb_xp, wb_f1, wb_f2,
                            wb_pw1, wb_pw1 + 262144, wb_pw2, wb_pw2 + 262144, wb_proj};
    int cnt4[NSEG] = {4194304 / 4, 2097152 / 4, 262144 / 4, 2097152 / 4, 2097152 / 4,
                      262144 / 4, 262144 / 4, 262144 / 4, 262144 / 4, 786432 / 4};
    int acc = 0;
    for (int s = 0; s < NSEG; ++s) { ca.src[s] = srcs[s]; ca.dst[s] = dsts[s]; ca.start4[s] = acc; acc += cnt4[s]; }
    cvt_all_kernel<<<2048, 256, 0, stream>>>(ca, acc);
  }

  hipMemcpyAsync(g, x, N_BLD * 4, hipMemcpyDeviceToDevice, stream);

  const long sBL = (long)LL * DD;  // 524288
  for (int i = 0; i < 2; ++i) {
    ln_kernel<<<1024, 256, 0, stream>>>(g, ln_w + i * 512, ln_b + i * 512, xnb);
    for (int dir = 0; dir < 2; ++dir) {
      int m = 2 * i + dir;
      const ushort_t* wi = wb_in + (long)m * 1048576;
      const float* bi = in_b + (long)m * 2048;
      // in-proj: 4096 x 2048 x 512 -> xzb (bf16)
      if (dir == 0)
        mgemm<128, 0, 1, 0, 0, 0, 1, 0><<<dim3(16, 32, 1), 256, 0, stream>>>(
            xnb, wi, bi, xzb, 512, 512, 512, 2048, 2048, 0, 0, 0, 1.f);
      else
        mgemm<128, 0, 1, 0, 1, 0, 1, 0><<<dim3(16, 32, 1), 256, 0, stream>>>(
            xnb, wi, bi, xzb, 512, 512, 512, 2048, 2048, 0, 0, 0, 1.f);
      mconv_kernel<<<16384, 256, 0, stream>>>(xzb, conv_w + (long)m * 4096,
                                              conv_b + (long)m * 1024, xcb);
      // xproj: 4096 x 64 x 1024, split-K x4 (atomic into zeroed xdb)
      zf_kernel<<<256, 256, 0, stream>>>(xdb);
      mgemm<64, 0, 0, 2, 0, 0, 0, 1><<<dim3(1, 32, 4), 256, 0, stream>>>(
          xcb, wb_xp + (long)m * 65536, nullptr, xdb, 256, 1024, 1024, 64, 64,
          0, 0, 0, 1.f);
      // dt-proj: 4096 x 1024 x 32 softplus -> dtb (bf16)
      gemm_kernel<3, 1, 1><<<dim3(16, 64, 1), 256, 0, stream>>>(
          xdb, dt_w + (long)m * 32768, dt_b + (long)m * 1024, dtb, 32, 64, 32, 1024, 1.f);
      scan1_kernel<<<1024, 256, 0, stream>>>(dtb, xcb, xdb, A_log + (long)m * 16384, hend, dts);
      scan2_kernel<<<256, 256, 0, stream>>>(hend, dts, A_log + (long)m * 16384, car);
      scan3_kernel<<<1024, 256, 0, stream>>>(dtb, xcb, xdb, A_log + (long)m * 16384, car,
                                             Dp + (long)m * 1024, xzb, yb);
      // out-proj: 4096 x 512 x 1024, split-K x4, g += 0.5*(...) atomically
      if (dir == 0)
        mgemm<64, 0, 1, 2, 0, 0, 0, 1><<<dim3(8, 32, 4), 256, 0, stream>>>(
            yb, wb_out + (long)m * 524288, out_b + (long)m * 512, g, 256, 1024, 1024, 512,
            512, 0, 0, 0, 0.5f);
      else
        mgemm<64, 0, 1, 2, 0, 1, 0, 1><<<dim3(8, 32, 4), 256, 0, stream>>>(
            yb, wb_out + (long)m * 524288, out_b + (long)m * 512, g, 256, 1024, 1024, 512,
            512, 0, 0, 0, 0.5f);
    }
    // FFN
    ln_kernel<<<1024, 256, 0, stream>>>(g, ffn_ln_w + i * 512, ffn_ln_b + i * 512, xnb);
    mgemm<128, 2, 1, 0, 0, 0, 1, 0><<<dim3(16, 32, 1), 256, 0, stream>>>(
        xnb, wb_f1 + (long)i * 1048576, ffn_b1 + (long)i * 2048, h1b, 512, 512, 512, 2048,
        2048, 0, 0, 0, 1.f);
    mgemm<64, 0, 1, 2, 0, 0, 0, 1><<<dim3(8, 32, 4), 256, 0, stream>>>(
        h1b, wb_f2 + (long)i * 1048576, ffn_b2 + (long)i * 512, g, 512, 2048, 2048, 512,
        512, 0, 0, 0, 1.f);
  }

  // ---------- locals ----------
  cvt_kernel<<<512, 256, 0, stream>>>(x, xbf, N_BLD);
  for (int k = 0; k < 2; ++k) {
    const ushort_t* pw1w = wb_pw1 + (long)k * 262144;
    const float* pw1b = k ? l7_pw1b : l5_pw1b;
    const float* dww  = k ? l7_dww  : l5_dww;
    const ushort_t* pw2w = wb_pw2 + (long)k * 262144;
    const float* pw2b = k ? l7_pw2b : l5_pw2b;
    // pw1: per batch  lh[b](D,L) = W(512x512) x xbf[b](1024x512)^T
    mgemm<64, 0, 2, 0, 0, 0, 0, 0><<<dim3(16, 4, 4), 256, 0, stream>>>(
        pw1w, xbf, pw1b, lh, 512, 512, 512, 1024, 1024, 0, sBL, sBL, 1.f);
    inorm_silu_kernel<<<2048, 256, 0, stream>>>(lh);
    if (k)
      dwconv_kernel<7><<<8192, 256, 0, stream>>>(lh, dww, lhc);
    else
      dwconv_kernel<5><<<8192, 256, 0, stream>>>(lh, dww, lhc);
    inorm_silu_kernel<<<2048, 256, 0, stream>>>(lhc);
    transpose_dl_kernel<<<dim3(32, 16, 4), dim3(32, 8), 0, stream>>>(lhc, lhT);
    // pw2: per batch  cat[b](1024, cols 512k..512k+512) = lhT[b](1024x512) x W^T -> bf16
    mgemm<64, 0, 1, 0, 0, 0, 1, 0><<<dim3(8, 8, 4), 256, 0, stream>>>(
        lhT, pw2w, pw2b, cat + (k ? 1024 : 512), 512, 512, 512, 1536, 512,
        sBL, 0, (long)LL * 1536, 1.f);
  }
  copyg_kernel<<<8192, 256, 0, stream>>>(g, cat);
  hipMemcpyAsync(outp, x, N_BLD * 4, hipMemcpyDeviceToDevice, stream);
  // out += cat(4096x1536) @ proj_w^T (512x1536), split-K x4 atomic
  mgemm<64, 0, 1, 2, 0, 0, 0, 1><<<dim3(8, 32, 4), 256, 0, stream>>>(
      cat, wb_proj, proj_b, outp, 384, 1536, 1536, 512, 512, 0, 0, 0, 1.f);
}

// Round 5
// 867.609 us; speedup vs baseline: 1.1286x; 1.1286x over previous
//
#include <hip/hip_runtime.h>
#include <hip/hip_bf16.h>
#include <math.h>

// ---------- problem constants ----------
#define BB 4
#define LL 1024
#define DD 512
#define DI 1024
#define NST 16
#define NC 64   // scan chunks
#define CL 16   // chunk length

typedef unsigned short ushort_t;
typedef __attribute__((ext_vector_type(8))) short short8;
typedef __attribute__((ext_vector_type(4))) float f32x4;
typedef __attribute__((ext_vector_type(4))) unsigned short ushort4_t;

__device__ __forceinline__ float silu_f(float x) { return x / (1.f + __expf(-x)); }

__device__ __forceinline__ ushort_t f2bf(float f) {
  union { float f; unsigned u; } v; v.f = f;
  unsigned r = v.u + 0x7fffu + ((v.u >> 16) & 1u);
  return (ushort_t)(r >> 16);
}
__device__ __forceinline__ float bf2f(ushort_t h) {
  union { unsigned u; float f; } v; v.u = ((unsigned)h) << 16;
  return v.f;
}

__device__ __forceinline__ void gl_lds16(const ushort_t* src, ushort_t* dst) {
  __builtin_amdgcn_global_load_lds(
      (const __attribute__((address_space(1))) void*)src,
      (__attribute__((address_space(3))) void*)dst, 16, 0, 0);
}

// ======================= bf16 MFMA GEMM (2-phase double-buffered) =======================
// C[m,n] = op( sum_k A[m,k]*Bt[n,k] + bias );  A: M x K bf16, Bt: N x K bf16
// BM=128, BK=64, 4 waves. BN=128: wave grid 2x2 (64x64/wave). BN=64: 4x1 (32x64).
// ACT: 0 none 1 silu 2 gelu 3 softplus ; BIASM: 0 none 1 col 2 row
// CMODE: 0 store, 1 += (f32) ; FLIPA/FLIPC: row ^ 1023 ; OUTBF: C bf16
// SPLITK: blockIdx.z = k-split; A/B advance zz*K, C advances zz*sC (partials)
template <int BN, int ACT, int BIASM, int CMODE, int FLIPA, int FLIPC, int OUTBF, int SPLITK>
__global__ __launch_bounds__(256) void mgemm(
    const ushort_t* __restrict__ A, const ushort_t* __restrict__ Bt,
    const float* __restrict__ bias, void* __restrict__ Cv,
    int K, int lda, int ldb, int ldc, int nreal,
    long sA, long sB, long sC, float scale) {
  constexpr int MREP = (BN == 128) ? 4 : 2;
  constexpr int WM = MREP * 16;          // per-wave M span
  constexpr int NB = BN / 32;            // B staging chunks per wave
  __shared__ ushort_t As[2][128 * 64];
  __shared__ ushort_t Bs[2][BN * 64];
  const int zz = blockIdx.z;
  const ushort_t* Ab = A + (SPLITK ? (long)zz * K : zz * sA);
  const ushort_t* Bb = Bt + (SPLITK ? (long)zz * K : zz * sB);
  // XCD-aware bijective swizzle (nwg divisible by 8 at every call site)
  const int flat = blockIdx.y * gridDim.x + blockIdx.x;
  const int nwg = gridDim.x * gridDim.y;
  const int id2 = (flat & 7) * (nwg >> 3) + (flat >> 3);
  const int bm = (id2 / gridDim.x) * 128;
  const int bn = (id2 % gridDim.x) * BN;
  const int tid = threadIdx.x;
  const int wave = tid >> 6, lane = tid & 63;
  const int rlo = lane & 15, q = lane >> 4;
  const int wr = (BN == 128) ? (wave >> 1) : wave;
  const int wc = (BN == 128) ? (wave & 1) : 0;

  f32x4 zero4 = {0.f, 0.f, 0.f, 0.f};
  f32x4 acc[MREP][4];
#pragma unroll
  for (int m = 0; m < MREP; ++m)
#pragma unroll
    for (int n = 0; n < 4; ++n) acc[m][n] = zero4;

  // staging: chunk c covers LDS bytes [c*1024, c*1024+1024)
  // lane writes 16B at c*1024+lane*16 -> row=c*8+lane/8, slot=lane&7
  // LDS[row][slot] holds global col-chunk (slot ^ (row&7))  (XOR involution)
  const int srow_off = lane >> 3;
  const int sslot = lane & 7;

#define STAGE_T(bb, k0)                                          \
  do {                                                           \
    _Pragma("unroll") for (int it = 0; it < 4; ++it) {           \
      int c = wave * 4 + it;                                     \
      int row = c * 8 + srow_off;                                \
      int gcol = ((sslot ^ (row & 7)) << 3);                     \
      int gra = bm + row;                                        \
      if (FLIPA) gra ^= 1023;                                    \
      gl_lds16(Ab + (long)gra * lda + (k0) + gcol, &As[bb][c * 512]); } \
    _Pragma("unroll") for (int it = 0; it < NB; ++it) {          \
      int c = wave * NB + it;                                    \
      int row = c * 8 + srow_off;                                \
      int gcol = ((sslot ^ (row & 7)) << 3);                     \
      gl_lds16(Bb + (long)(bn + row) * ldb + (k0) + gcol, &Bs[bb][c * 512]); } \
  } while (0)

  const int nt = K >> 6;
  STAGE_T(0, 0);
  __syncthreads();  // implicit vmcnt(0) drain
  int cur = 0;
  for (int t = 0; t < nt; ++t) {
    if (t + 1 < nt) STAGE_T(cur ^ 1, (t + 1) * 64);  // prefetch next tile
#pragma unroll
    for (int ks = 0; ks < 2; ++ks) {
      short8 af[MREP], bf[4];
#pragma unroll
      for (int m = 0; m < MREP; ++m) {
        int row = wr * WM + m * 16 + rlo;
        int ch = (ks * 4 + q) ^ (row & 7);
        af[m] = *(const short8*)&As[cur][row * 64 + ch * 8];
      }
#pragma unroll
      for (int n = 0; n < 4; ++n) {
        int row = wc * 64 + n * 16 + rlo;
        int ch = (ks * 4 + q) ^ (row & 7);
        bf[n] = *(const short8*)&Bs[cur][row * 64 + ch * 8];
      }
#pragma unroll
      for (int m = 0; m < MREP; ++m)
#pragma unroll
        for (int n = 0; n < 4; ++n)
          acc[m][n] = __builtin_amdgcn_mfma_f32_16x16x32_bf16(af[m], bf[n], acc[m][n], 0, 0, 0);
    }
    __syncthreads();  // drains prefetch vmcnt + all lgkm; next buffer ready
    cur ^= 1;
  }
#undef STAGE_T

  // epilogue: C/D layout col=lane&15, row=q*4+j  [m89]
#pragma unroll
  for (int m = 0; m < MREP; ++m) {
#pragma unroll
    for (int n = 0; n < 4; ++n) {
      int col = bn + wc * 64 + n * 16 + rlo;
      bool cok = (col < nreal);
#pragma unroll
      for (int j = 0; j < 4; ++j) {
        int row = bm + wr * WM + m * 16 + q * 4 + j;
        int orow = FLIPC ? (row ^ 1023) : row;
        float v = acc[m][n][j];
        if (!SPLITK || zz == 0) {
          if (BIASM == 1) v += bias[col];
          else if (BIASM == 2) v += bias[row];
        }
        if (ACT == 1) v = silu_f(v);
        else if (ACT == 2) v = 0.5f * v * (1.f + erff(v * 0.70710678118654752f));
        else if (ACT == 3) v = (v > 20.f) ? v : log1pf(__expf(v));
        if (cok) {
          if (OUTBF) {
            ushort_t* C = (ushort_t*)Cv + (long)zz * sC;
            C[(long)orow * ldc + col] = f2bf(scale * v);
          } else {
            float* C = (float*)Cv + (long)zz * sC;
            if (CMODE == 1) C[(long)orow * ldc + col] += scale * v;
            else C[(long)orow * ldc + col] = scale * v;
          }
        }
      }
    }
  }
}

// ======================= fused f32 -> bf16 weight conversion =======================
#define NSEG 10
struct CvtArgs {
  const float* src[NSEG];
  ushort_t* dst[NSEG];
  int start4[NSEG];  // prefix offsets in float4 units
};
__global__ __launch_bounds__(256) void cvt_all_kernel(CvtArgs a, int total4) {
  int i = blockIdx.x * 256 + threadIdx.x;
  int stride = gridDim.x * 256;
  for (; i < total4; i += stride) {
    int seg = 0;
#pragma unroll
    for (int s = 1; s < NSEG; ++s)
      if (i >= a.start4[s]) seg = s;
    int off = i - a.start4[seg];
    float4 v = ((const float4*)a.src[seg])[off];
    ushort4_t o;
    o.x = f2bf(v.x); o.y = f2bf(v.y); o.z = f2bf(v.z); o.w = f2bf(v.w);
    *(ushort4_t*)(a.dst[seg] + (long)off * 4) = o;
  }
}

// plain cvt (x -> bf16, locals phase)
__global__ __launch_bounds__(256) void cvt_kernel(const float* __restrict__ in,
                                                  ushort_t* __restrict__ out, long n) {
  long i = (long)blockIdx.x * 256 + threadIdx.x;
  long stride = (long)gridDim.x * 256;
  for (; i < n; i += stride) out[i] = f2bf(in[i]);
}

// ======================= reduce 4 split-K partials =======================
__global__ __launch_bounds__(256) void reduce4_kernel(const float* __restrict__ p,
                                                      float* __restrict__ o) {
  int i = blockIdx.x * 256 + threadIdx.x;  // 65536 float4s
  const float4* p4 = (const float4*)p;
  float4 a = p4[i], b = p4[i + 65536], c = p4[i + 131072], d = p4[i + 196608];
  float4 r;
  r.x = a.x + b.x + c.x + d.x;
  r.y = a.y + b.y + c.y + d.y;
  r.z = a.z + b.z + c.z + d.z;
  r.w = a.w + b.w + c.w + d.w;
  ((float4*)o)[i] = r;
}

// ======================= LayerNorm (wave per row, D=512) -> bf16 =======================
__global__ __launch_bounds__(256) void ln_kernel(
    const float* __restrict__ x, const float* __restrict__ w,
    const float* __restrict__ b, ushort_t* __restrict__ o) {
  int row = blockIdx.x * 4 + (threadIdx.x >> 6);
  int lane = threadIdx.x & 63;
  const float* xr = x + (long)row * DD + lane * 8;
  float v[8];
  *(float4*)&v[0] = *(const float4*)&xr[0];
  *(float4*)&v[4] = *(const float4*)&xr[4];
  float s = 0.f, qq = 0.f;
#pragma unroll
  for (int k = 0; k < 8; ++k) { s += v[k]; qq += v[k] * v[k]; }
#pragma unroll
  for (int off = 1; off < 64; off <<= 1) {
    s += __shfl_xor(s, off);
    qq += __shfl_xor(qq, off);
  }
  float mean = s * (1.f / DD);
  float rs = rsqrtf(qq * (1.f / DD) - mean * mean + 1e-5f);
  int c = lane * 8;
  short8 ov;
#pragma unroll
  for (int k = 0; k < 8; ++k)
    ov[k] = (short)f2bf((v[k] - mean) * rs * w[c + k] + b[c + k]);
  *(short8*)&o[(long)row * DD + c] = ov;
}

// ============== InstanceNorm over L + SiLU, in place (f32) ==============
__global__ __launch_bounds__(256) void inorm_silu_kernel(float* __restrict__ h) {
  long row = blockIdx.x;
  float* p = h + row * (long)LL;
  int t = threadIdx.x;
  float4 v = *(const float4*)&p[t * 4];
  float s = v.x + v.y + v.z + v.w;
  float q = v.x * v.x + v.y * v.y + v.z * v.z + v.w * v.w;
#pragma unroll
  for (int off = 1; off < 64; off <<= 1) {
    s += __shfl_xor(s, off);
    q += __shfl_xor(q, off);
  }
  __shared__ float ss[4], sq[4];
  int wv = t >> 6;
  if ((t & 63) == 0) { ss[wv] = s; sq[wv] = q; }
  __syncthreads();
  s = ss[0] + ss[1] + ss[2] + ss[3];
  q = sq[0] + sq[1] + sq[2] + sq[3];
  float mean = s * (1.f / LL);
  float rs = rsqrtf(q * (1.f / LL) - mean * mean + 1e-5f);
  v.x = silu_f((v.x - mean) * rs);
  v.y = silu_f((v.y - mean) * rs);
  v.z = silu_f((v.z - mean) * rs);
  v.w = silu_f((v.w - mean) * rs);
  *(float4*)&p[t * 4] = v;
}

// ============== Mamba causal depthwise conv (KC=4) + bias + SiLU (bf16 in/out) ==============
__global__ __launch_bounds__(256) void mconv_kernel(
    const ushort_t* __restrict__ xz, const float* __restrict__ cw,
    const float* __restrict__ cb, ushort_t* __restrict__ xc) {
  long i = (long)blockIdx.x * 256 + threadIdx.x;  // over B*L*DI
  int d = (int)(i & (DI - 1));
  long bt = i >> 10;
  int t = (int)(bt & (LL - 1));
  const ushort_t* col = xz + d;
  long r = bt * (2 * DI);
  float w0 = cw[d * 4 + 0], w1 = cw[d * 4 + 1], w2 = cw[d * 4 + 2], w3 = cw[d * 4 + 3];
  float acc = cb[d];
  if (t >= 3) acc += bf2f(col[r - 3 * 2 * DI]) * w0;
  if (t >= 2) acc += bf2f(col[r - 2 * 2 * DI]) * w1;
  if (t >= 1) acc += bf2f(col[r - 1 * 2 * DI]) * w2;
  acc += bf2f(col[r]) * w3;
  xc[i] = f2bf(silu_f(acc));
}

// ============== local depthwise conv over L, 'same' padding (f32) ==============
template <int KW>
__global__ __launch_bounds__(256) void dwconv_kernel(
    const float* __restrict__ in, const float* __restrict__ w, float* __restrict__ out) {
  long i = (long)blockIdx.x * 256 + threadIdx.x;  // over B*D*L
  int l = (int)(i & (LL - 1));
  long bd = i >> 10;
  int d = (int)(bd & (DD - 1));
  const float* row = in + bd * (long)LL;
  float acc = 0.f;
#pragma unroll
  for (int j = 0; j < KW; ++j) {
    int ll = l + j - KW / 2;
    if (ll >= 0 && ll < LL) acc += row[ll] * w[d * KW + j];
  }
  out[i] = acc;
}

// ============== transpose (B, D, L) f32 -> (B, L, D) bf16 ==============
__global__ void transpose_dl_kernel(const float* __restrict__ in, ushort_t* __restrict__ out) {
  __shared__ float tile[32][33];
  int b = blockIdx.z;
  int l0 = blockIdx.x * 32, d0 = blockIdx.y * 32;
  int tx = threadIdx.x, ty = threadIdx.y;  // (32, 8)
  const float* ib = in + (long)b * DD * LL;
  ushort_t* ob = out + (long)b * LL * DD;
#pragma unroll
  for (int r = 0; r < 4; ++r)
    tile[ty + 8 * r][tx] = ib[(long)(d0 + ty + 8 * r) * LL + l0 + tx];
  __syncthreads();
#pragma unroll
  for (int r = 0; r < 4; ++r)
    ob[(long)(l0 + ty + 8 * r) * DD + d0 + tx] = f2bf(tile[tx][ty + 8 * r]);
}

// ============== g (f32) -> cat bf16 columns [0,512) ==============
__global__ __launch_bounds__(256) void copyg_kernel(const float* __restrict__ g,
                                                    ushort_t* __restrict__ cat) {
  long i = (long)blockIdx.x * 256 + threadIdx.x;  // 4096*512
  long r = i >> 9;
  int c = (int)(i & 511);
  cat[r * 1536 + c] = f2bf(g[i]);
}

// ======================= selective scan, 3-pass chunked (NC=64, CL=16) =======================
__global__ __launch_bounds__(256) void scan1_kernel(
    const ushort_t* __restrict__ dt, const ushort_t* __restrict__ xc,
    const float* __restrict__ xdb, const float* __restrict__ A_log,
    float* __restrict__ hend, float* __restrict__ dts) {
  int idx = blockIdx.x * 256 + threadIdx.x;  // B*NC*DI = 262144
  int d = idx & (DI - 1);
  int c = (idx >> 10) & (NC - 1);
  int b = idx >> 16;
  float Ac[NST];
  {
    const float4* ap = (const float4*)(A_log + d * NST);
#pragma unroll
    for (int k = 0; k < 4; ++k) {
      float4 a = ap[k];
      Ac[4 * k + 0] = -__expf(a.x);
      Ac[4 * k + 1] = -__expf(a.y);
      Ac[4 * k + 2] = -__expf(a.z);
      Ac[4 * k + 3] = -__expf(a.w);
    }
  }
  long rowbase = (long)b * LL + c * CL;
  float ldts[CL], lxs[CL];
#pragma unroll
  for (int tt = 0; tt < CL; ++tt) {
    long r = rowbase + tt;
    ldts[tt] = bf2f(dt[r * DI + d]);
    lxs[tt] = bf2f(xc[r * DI + d]);
  }
  float h[NST] = {};
  float ds = 0.f;
#pragma unroll
  for (int tt = 0; tt < CL; ++tt) {
    ds += ldts[tt];
    float coef = ldts[tt] * lxs[tt];
    const float4* brow = (const float4*)&xdb[(rowbase + tt) * 64 + 32];
    float bv[NST];
#pragma unroll
    for (int k = 0; k < 4; ++k) {
      float4 bb = brow[k];
      bv[4 * k + 0] = bb.x; bv[4 * k + 1] = bb.y; bv[4 * k + 2] = bb.z; bv[4 * k + 3] = bb.w;
    }
#pragma unroll
    for (int n = 0; n < NST; ++n) h[n] = h[n] * __expf(Ac[n] * ldts[tt]) + coef * bv[n];
  }
  long o = ((long)(b * DI + d) * NC + c) * NST;
  float4* ho = (float4*)(hend + o);
#pragma unroll
  for (int k = 0; k < 4; ++k) {
    float4 hv = {h[4 * k], h[4 * k + 1], h[4 * k + 2], h[4 * k + 3]};
    ho[k] = hv;
  }
  dts[((long)b * NC + c) * DI + d] = ds;
}

__global__ __launch_bounds__(256) void scan2_kernel(
    const float* __restrict__ hend, const float* __restrict__ dts,
    const float* __restrict__ A_log, float* __restrict__ carries) {
  int idx = blockIdx.x * 256 + threadIdx.x;  // B*DI*NST = 65536
  int n = idx & (NST - 1);
  int d = (idx >> 4) & (DI - 1);
  int b = idx >> 14;
  float Ac = -__expf(A_log[d * NST + n]);
  float e[NC];
#pragma unroll
  for (int c = 0; c < NC; ++c)
    e[c] = __expf(Ac * dts[((long)b * NC + c) * DI + d]);
  float carry = 0.f;
  long base = (long)(b * DI + d) * NC * NST + n;
#pragma unroll
  for (int c = 0; c < NC; ++c) {
    carries[base + c * NST] = carry;
    carry = carry * e[c] + hend[base + c * NST];
  }
}

__global__ __launch_bounds__(256) void scan3_kernel(
    const ushort_t* __restrict__ dt, const ushort_t* __restrict__ xc,
    const float* __restrict__ xdb, const float* __restrict__ A_log,
    const float* __restrict__ carries, const float* __restrict__ Dp,
    const ushort_t* __restrict__ xz, ushort_t* __restrict__ y) {
  int idx = blockIdx.x * 256 + threadIdx.x;
  int d = idx & (DI - 1);
  int c = (idx >> 10) & (NC - 1);
  int b = idx >> 16;
  float Ac[NST];
  {
    const float4* ap = (const float4*)(A_log + d * NST);
#pragma unroll
    for (int k = 0; k < 4; ++k) {
      float4 a = ap[k];
      Ac[4 * k + 0] = -__expf(a.x);
      Ac[4 * k + 1] = -__expf(a.y);
      Ac[4 * k + 2] = -__expf(a.z);
      Ac[4 * k + 3] = -__expf(a.w);
    }
  }
  float h[NST];
  long o = ((long)(b * DI + d) * NC + c) * NST;
  {
    const float4* co = (const float4*)(carries + o);
#pragma unroll
    for (int k = 0; k < 4; ++k) {
      float4 cv = co[k];
      h[4 * k + 0] = cv.x; h[4 * k + 1] = cv.y; h[4 * k + 2] = cv.z; h[4 * k + 3] = cv.w;
    }
  }
  float Dv = Dp[d];
  long rowbase = (long)b * LL + c * CL;
  float ldts[CL], lxs[CL];
#pragma unroll
  for (int tt = 0; tt < CL; ++tt) {
    long r = rowbase + tt;
    ldts[tt] = bf2f(dt[r * DI + d]);
    lxs[tt] = bf2f(xc[r * DI + d]);
  }
#pragma unroll
  for (int tt = 0; tt < CL; ++tt) {
    long r = rowbase + tt;
    float coef = ldts[tt] * lxs[tt];
    const float4* brow = (const float4*)&xdb[r * 64 + 32];
    float bv[NST], cv[NST];
#pragma unroll
    for (int k = 0; k < 4; ++k) {
      float4 bb = brow[k];
      bv[4 * k + 0] = bb.x; bv[4 * k + 1] = bb.y; bv[4 * k + 2] = bb.z; bv[4 * k + 3] = bb.w;
      float4 cc = brow[k + 4];
      cv[4 * k + 0] = cc.x; cv[4 * k + 1] = cc.y; cv[4 * k + 2] = cc.z; cv[4 * k + 3] = cc.w;
    }
    float acc = 0.f;
#pragma unroll
    for (int n = 0; n < NST; ++n) {
      h[n] = h[n] * __expf(Ac[n] * ldts[tt]) + coef * bv[n];
      acc += h[n] * cv[n];
    }
    float yv = acc + lxs[tt] * Dv;
    float zv = bf2f(xz[r * (2 * DI) + DI + d]);
    y[r * DI + d] = f2bf(yv * silu_f(zv));
  }
}

// ======================= f32 tiled GEMM (dt-proj only, K=32) =======================
template <int ACT, int BIASM, int OUTBF>
__global__ __launch_bounds__(256) void gemm_kernel(
    const float* __restrict__ A, const float* __restrict__ Bt,
    const float* __restrict__ bias, void* __restrict__ Cv,
    int K, int lda, int ldb, int ldc, float scale) {
  const int bm = blockIdx.y * 64, bn = blockIdx.x * 64;
  __shared__ float As[64][32];
  __shared__ float Bs[32][64];
  const int tid = threadIdx.x;
  const int tx = tid & 15, ty = tid >> 4;
  float acc[4][4] = {};
  for (int k0 = 0; k0 < K; k0 += 32) {
#pragma unroll
    for (int it = 0; it < 2; ++it) {
      int e = tid + it * 256;
      int r = e >> 3;
      int kq = (e & 7) << 2;
      float4 va = *(const float4*)(A + (long)(bm + r) * lda + k0 + kq);
      *(float4*)&As[r][kq] = va;
      float4 vb = *(const float4*)(Bt + (long)(bn + r) * ldb + k0 + kq);
      Bs[kq + 0][r] = vb.x;
      Bs[kq + 1][r] = vb.y;
      Bs[kq + 2][r] = vb.z;
      Bs[kq + 3][r] = vb.w;
    }
    __syncthreads();
#pragma unroll
    for (int kk = 0; kk < 32; kk += 4) {
      float4 a4[4], b4[4];
#pragma unroll
      for (int i = 0; i < 4; ++i) a4[i] = *(const float4*)&As[ty * 4 + i][kk];
#pragma unroll
      for (int c = 0; c < 4; ++c) b4[c] = *(const float4*)&Bs[kk + c][tx * 4];
#pragma unroll
      for (int c = 0; c < 4; ++c) {
        float4 bb = b4[c];
#pragma unroll
        for (int i = 0; i < 4; ++i) {
          float av = (c == 0) ? a4[i].x : (c == 1) ? a4[i].y : (c == 2) ? a4[i].z : a4[i].w;
          acc[i][0] += av * bb.x;
          acc[i][1] += av * bb.y;
          acc[i][2] += av * bb.z;
          acc[i][3] += av * bb.w;
        }
      }
    }
    __syncthreads();
  }
#pragma unroll
  for (int i = 0; i < 4; ++i) {
    int row = bm + ty * 4 + i;
#pragma unroll
    for (int j = 0; j < 4; ++j) {
      int col = bn + tx * 4 + j;
      float v = acc[i][j];
      if (BIASM == 1) v += bias[col];
      else if (BIASM == 2) v += bias[row];
      if (ACT == 1) v = silu_f(v);
      else if (ACT == 2) v = 0.5f * v * (1.f + erff(v * 0.70710678118654752f));
      else if (ACT == 3) v = (v > 20.f) ? v : log1pf(__expf(v));
      if (OUTBF) ((ushort_t*)Cv)[(long)row * ldc + col] = f2bf(scale * v);
      else ((float*)Cv)[(long)row * ldc + col] = scale * v;
    }
  }
}

// ======================= host launch =======================
extern "C" void kernel_launch(void* const* d_in, const int* in_sizes, int n_in,
                              void* d_out, int out_size, void* d_ws, size_t ws_size,
                              hipStream_t stream) {
  const float* x        = (const float*)d_in[0];
  const float* in_w     = (const float*)d_in[1];
  const float* in_b     = (const float*)d_in[2];
  const float* conv_w   = (const float*)d_in[3];
  const float* conv_b   = (const float*)d_in[4];
  const float* xp_w     = (const float*)d_in[5];
  const float* dt_w     = (const float*)d_in[6];
  const float* dt_b     = (const float*)d_in[7];
  const float* A_log    = (const float*)d_in[8];
  const float* Dp       = (const float*)d_in[9];
  const float* out_w    = (const float*)d_in[10];
  const float* out_b    = (const float*)d_in[11];
  const float* ln_w     = (const float*)d_in[12];
  const float* ln_b     = (const float*)d_in[13];
  const float* ffn_ln_w = (const float*)d_in[14];
  const float* ffn_ln_b = (const float*)d_in[15];
  const float* ffn_w1   = (const float*)d_in[16];
  const float* ffn_b1   = (const float*)d_in[17];
  const float* ffn_w2   = (const float*)d_in[18];
  const float* ffn_b2   = (const float*)d_in[19];
  const float* l5_pw1w  = (const float*)d_in[20];
  const float* l5_pw1b  = (const float*)d_in[21];
  const float* l5_dww   = (const float*)d_in[22];
  const float* l5_pw2w  = (const float*)d_in[23];
  const float* l5_pw2b  = (const float*)d_in[24];
  const float* l7_pw1w  = (const float*)d_in[25];
  const float* l7_pw1b  = (const float*)d_in[26];
  const float* l7_dww   = (const float*)d_in[27];
  const float* l7_pw2w  = (const float*)d_in[28];
  const float* l7_pw2b  = (const float*)d_in[29];
  const float* proj_w   = (const float*)d_in[30];
  const float* proj_b   = (const float*)d_in[31];
  float* outp = (float*)d_out;

  // ---------- workspace layout ----------
  const long N_BLD = (long)BB * LL * DD;  // 2,097,152
  ushort_t* wb_in  = (ushort_t*)d_ws;          // 4,194,304
  ushort_t* wb_out = wb_in + 4194304;          // 2,097,152
  ushort_t* wb_xp  = wb_out + 2097152;         // 262,144 (4 x 64 x 1024)
  ushort_t* wb_f1  = wb_xp + 262144;           // 2,097,152
  ushort_t* wb_f2  = wb_f1 + 2097152;          // 2,097,152
  ushort_t* wb_pw1 = wb_f2 + 2097152;          // 524,288 (k5 @0, k7 @262144)
  ushort_t* wb_pw2 = wb_pw1 + 524288;          // 524,288
  ushort_t* wb_proj= wb_pw2 + 524288;          // 786,432
  ushort_t* xnb    = wb_proj + 786432;         // 2,097,152 bf16
  float* g = (float*)(xnb + 2097152);          // 2,097,152 f32
  char* arena = (char*)(g + 2097152);
  // mamba/ffn phase
  ushort_t* xzb = (ushort_t*)arena;            // 8,388,608 ushort (4096 x 2048)
  ushort_t* xcb = xzb + 8388608;               // 4,194,304 ushort
  float* xdb  = (float*)(xcb + 4194304);       // 262,144 f32
  ushort_t* dtb = (ushort_t*)(xdb + 262144);   // 4,194,304 ushort
  ushort_t* yb = dtb + 4194304;                // 4,194,304 ushort
  float* hend = (float*)(yb + 4194304);        // 4,194,304 f32
  float* dts  = hend + 4194304;                // 262,144 f32
  float* car  = dts + 262144;                  // 4,194,304 f32
  float* xdbp = car;                           // 1,048,576 f32 (xproj partials, dead before scan2)
  ushort_t* h1b = (ushort_t*)hend;             // 8,388,608 ushort (FFN h1; hend dead by FFN)
  // locals overlay (mamba scratch dead)
  ushort_t* xbf = (ushort_t*)arena;            // 2,097,152 ushort
  float* lh  = (float*)(xbf + 2097152);        // 2,097,152 f32
  float* lhc = lh + 2097152;                   // 2,097,152 f32
  ushort_t* lhT = (ushort_t*)(lhc + 2097152);  // 2,097,152 ushort
  ushort_t* cat = lhT + 2097152;               // 6,291,456 ushort
  size_t need = (size_t)((char*)(car + 4194304) - (char*)d_ws);
  if (ws_size < need) return;

  // ---------- fused weight conversions (bf16) ----------
  {
    CvtArgs ca;
    const float* srcs[NSEG] = {in_w, out_w, xp_w, ffn_w1, ffn_w2,
                               l5_pw1w, l7_pw1w, l5_pw2w, l7_pw2w, proj_w};
    ushort_t* dsts[NSEG] = {wb_in, wb_out, wb_xp, wb_f1, wb_f2,
                            wb_pw1, wb_pw1 + 262144, wb_pw2, wb_pw2 + 262144, wb_proj};
    int cnt4[NSEG] = {4194304 / 4, 2097152 / 4, 262144 / 4, 2097152 / 4, 2097152 / 4,
                      262144 / 4, 262144 / 4, 262144 / 4, 262144 / 4, 786432 / 4};
    int acc = 0;
    for (int s = 0; s < NSEG; ++s) { ca.src[s] = srcs[s]; ca.dst[s] = dsts[s]; ca.start4[s] = acc; acc += cnt4[s]; }
    cvt_all_kernel<<<2048, 256, 0, stream>>>(ca, acc);
  }

  hipMemcpyAsync(g, x, N_BLD * 4, hipMemcpyDeviceToDevice, stream);

  const long sBL = (long)LL * DD;  // 524288
  for (int i = 0; i < 2; ++i) {
    ln_kernel<<<1024, 256, 0, stream>>>(g, ln_w + i * 512, ln_b + i * 512, xnb);
    for (int dir = 0; dir < 2; ++dir) {
      int m = 2 * i + dir;
      const ushort_t* wi = wb_in + (long)m * 1048576;
      const float* bi = in_b + (long)m * 2048;
      // in-proj: 4096 x 2048 x 512 -> xzb (bf16)
      if (dir == 0)
        mgemm<128, 0, 1, 0, 0, 0, 1, 0><<<dim3(16, 32, 1), 256, 0, stream>>>(
            xnb, wi, bi, xzb, 512, 512, 512, 2048, 2048, 0, 0, 0, 1.f);
      else
        mgemm<128, 0, 1, 0, 1, 0, 1, 0><<<dim3(16, 32, 1), 256, 0, stream>>>(
            xnb, wi, bi, xzb, 512, 512, 512, 2048, 2048, 0, 0, 0, 1.f);
      mconv_kernel<<<16384, 256, 0, stream>>>(xzb, conv_w + (long)m * 4096,
                                              conv_b + (long)m * 1024, xcb);
      // xproj: 4096 x 64 x 1024, split-K x4 -> partials, then reduce
      mgemm<64, 0, 0, 0, 0, 0, 0, 1><<<dim3(1, 32, 4), 256, 0, stream>>>(
          xcb, wb_xp + (long)m * 65536, nullptr, xdbp, 256, 1024, 1024, 64, 64,
          0, 0, 262144, 1.f);
      reduce4_kernel<<<256, 256, 0, stream>>>(xdbp, xdb);
      // dt-proj: 4096 x 1024 x 32 softplus -> dtb (bf16)
      gemm_kernel<3, 1, 1><<<dim3(16, 64, 1), 256, 0, stream>>>(
          xdb, dt_w + (long)m * 32768, dt_b + (long)m * 1024, dtb, 32, 64, 32, 1024, 1.f);
      scan1_kernel<<<1024, 256, 0, stream>>>(dtb, xcb, xdb, A_log + (long)m * 16384, hend, dts);
      scan2_kernel<<<256, 256, 0, stream>>>(hend, dts, A_log + (long)m * 16384, car);
      scan3_kernel<<<1024, 256, 0, stream>>>(dtb, xcb, xdb, A_log + (long)m * 16384, car,
                                             Dp + (long)m * 1024, xzb, yb);
      // out-proj: 4096 x 512 x 1024, g += 0.5*(...)
      if (dir == 0)
        mgemm<64, 0, 1, 1, 0, 0, 0, 0><<<dim3(8, 32, 1), 256, 0, stream>>>(
            yb, wb_out + (long)m * 524288, out_b + (long)m * 512, g, 1024, 1024, 1024, 512,
            512, 0, 0, 0, 0.5f);
      else
        mgemm<64, 0, 1, 1, 0, 1, 0, 0><<<dim3(8, 32, 1), 256, 0, stream>>>(
            yb, wb_out + (long)m * 524288, out_b + (long)m * 512, g, 1024, 1024, 1024, 512,
            512, 0, 0, 0, 0.5f);
    }
    // FFN
    ln_kernel<<<1024, 256, 0, stream>>>(g, ffn_ln_w + i * 512, ffn_ln_b + i * 512, xnb);
    mgemm<128, 2, 1, 0, 0, 0, 1, 0><<<dim3(16, 32, 1), 256, 0, stream>>>(
        xnb, wb_f1 + (long)i * 1048576, ffn_b1 + (long)i * 2048, h1b, 512, 512, 512, 2048,
        2048, 0, 0, 0, 1.f);
    mgemm<64, 0, 1, 1, 0, 0, 0, 0><<<dim3(8, 32, 1), 256, 0, stream>>>(
        h1b, wb_f2 + (long)i * 1048576, ffn_b2 + (long)i * 512, g, 2048, 2048, 2048, 512,
        512, 0, 0, 0, 1.f);
  }

  // ---------- locals ----------
  cvt_kernel<<<512, 256, 0, stream>>>(x, xbf, N_BLD);
  for (int k = 0; k < 2; ++k) {
    const ushort_t* pw1w = wb_pw1 + (long)k * 262144;
    const float* pw1b = k ? l7_pw1b : l5_pw1b;
    const float* dww  = k ? l7_dww  : l5_dww;
    const ushort_t* pw2w = wb_pw2 + (long)k * 262144;
    const float* pw2b = k ? l7_pw2b : l5_pw2b;
    // pw1: per batch  lh[b](D,L) = W(512x512) x xbf[b](1024x512)^T
    mgemm<64, 0, 2, 0, 0, 0, 0, 0><<<dim3(16, 4, 4), 256, 0, stream>>>(
        pw1w, xbf, pw1b, lh, 512, 512, 512, 1024, 1024, 0, sBL, sBL, 1.f);
    inorm_silu_kernel<<<2048, 256, 0, stream>>>(lh);
    if (k)
      dwconv_kernel<7><<<8192, 256, 0, stream>>>(lh, dww, lhc);
    else
      dwconv_kernel<5><<<8192, 256, 0, stream>>>(lh, dww, lhc);
    inorm_silu_kernel<<<2048, 256, 0, stream>>>(lhc);
    transpose_dl_kernel<<<dim3(32, 16, 4), dim3(32, 8), 0, stream>>>(lhc, lhT);
    // pw2: per batch  cat[b](1024, cols 512k..512k+512) = lhT[b](1024x512) x W^T -> bf16
    mgemm<64, 0, 1, 0, 0, 0, 1, 0><<<dim3(8, 8, 4), 256, 0, stream>>>(
        lhT, pw2w, pw2b, cat + (k ? 1024 : 512), 512, 512, 512, 1536, 512,
        sBL, 0, (long)LL * 1536, 1.f);
  }
  copyg_kernel<<<8192, 256, 0, stream>>>(g, cat);
  hipMemcpyAsync(outp, x, N_BLD * 4, hipMemcpyDeviceToDevice, stream);
  // out += cat(4096x1536) @ proj_w^T (512x1536)
  mgemm<64, 0, 1, 1, 0, 0, 0, 0><<<dim3(8, 32, 1), 256, 0, stream>>>(
      cat, wb_proj, proj_b, outp, 1536, 1536, 1536, 512, 512, 0, 0, 0, 1.f);
}